// Round 1
// 174.364 us; speedup vs baseline: 1.0105x; 1.0105x over previous
//
#include <hip/hip_runtime.h>
#include <cstdint>
#include <cstddef>

#define B_  8
#define T_  1024
#define C_  768
#define H_  12
#define HD_ 64
#define K3_ 2304   // 3*C
#define NT_ 24     // K / 32

typedef unsigned short u16;
typedef __attribute__((ext_vector_type(8))) short bf16x8;   // 8 bf16 (4 VGPRs)
typedef __attribute__((ext_vector_type(4))) float f32x4;    // 4 fp32 acc

#define MFMA __builtin_amdgcn_mfma_f32_16x16x32_bf16

__device__ __forceinline__ u16 f2bf(float f) {
    unsigned u = __builtin_bit_cast(unsigned, f);
    u += 0x7fffu + ((u >> 16) & 1u);           // round-to-nearest-even
    return (u16)(u >> 16);
}

// pack two fp32 -> bf16x2 dword (round-half-up; P>=0, feeds bf16 MFMA)
__device__ __forceinline__ unsigned pk2bf(float a, float b) {
    unsigned ua = __builtin_bit_cast(unsigned, a) + 0x8000u;
    unsigned ub = __builtin_bit_cast(unsigned, b) + 0x8000u;
    return (ua >> 16) | (ub & 0xffff0000u);
}

// async global->LDS, 16 B per lane. LDS dest = wave-uniform base + lane*16.
#define GLL16(gp, lp) __builtin_amdgcn_global_load_lds( \
    (__attribute__((address_space(1))) unsigned int*)(gp), \
    (__attribute__((address_space(3))) unsigned int*)(lp), 16, 0, 0)

// ---------------- prep: x->bf16 + both weight transposes, one kernel ----------------
__device__ __forceinline__ void tcvt_tile(const float* __restrict__ in, u16* __restrict__ out,
                                          int R, int Cc, int bx, int by, int tid, float* tile /*32x33*/) {
    int bc = bx * 32, br = by * 32;
    int tx = tid & 31, ty = tid >> 5;   // (32, 8)
    #pragma unroll
    for (int kk = 0; kk < 32; kk += 8)
        tile[(ty + kk) * 33 + tx] = in[(size_t)(br + ty + kk) * Cc + bc + tx];
    __syncthreads();
    #pragma unroll
    for (int kk = 0; kk < 32; kk += 8)
        out[(size_t)(bc + ty + kk) * R + br + tx] = f2bf(tile[tx * 33 + ty + kk]);
}

__global__ void prep(const float* __restrict__ x, u16* __restrict__ xb,
                     const float* __restrict__ wa, u16* __restrict__ wat,
                     const float* __restrict__ wp, u16* __restrict__ wpt) {
    __shared__ float tile[32 * 33];
    int bid = blockIdx.x, tid = threadIdx.x;
    if (bid < 6144) {                      // cvt: 8192*768/4 elements of float4
        int i = bid * 256 + tid;
        float4 v = ((const float4*)x)[i];
        ushort4 o;
        o.x = f2bf(v.x); o.y = f2bf(v.y); o.z = f2bf(v.z); o.w = f2bf(v.w);
        ((ushort4*)xb)[i] = o;
    } else if (bid < 6144 + 1728) {        // w_attn [768][2304] -> [2304][768]
        int b = bid - 6144;
        tcvt_tile(wa, wat, C_, K3_, b % 72, b / 72, tid, tile);
    } else {                               // w_proj [768][768] -> [768][768]^T
        int b = bid - 7872;
        tcvt_tile(wp, wpt, C_, C_, b % 24, b / 24, tid, tile);
    }
}

// ---------------- GEMM core schedule (T3+T4+T5): BK=32, 3-buf circular LDS, ----------
// counted vmcnt(4) (never 0 in loop), one raw s_barrier per K-step, setprio on MFMA.
// Iter kt: STAGE(kt+2 -> buf[(kt+2)%3])  [WAR-safe: that buf's reads finished before the
// previous barrier]; ds_read buf[kt%3]; 16 MFMA; vmcnt(4) [kt+1 landed, kt+2 in flight];
// s_barrier. Prologue stages kt0,kt1; vmcnt(4) ensures kt0 landed chip-wide after barrier.

#define STG(Ag, Bg, Ls, ktv, b) { \
    _Pragma("unroll") \
    for (int s_ = 0; s_ < 2; s_++) { \
        GLL16(Ag + (size_t)(s_ * 64) * C_ + (ktv) * 32, Ls + (b) * 8192 + s_ * 2048); \
        GLL16(Bg + (size_t)(s_ * 64) * C_ + (ktv) * 32, Ls + (b) * 8192 + 4096 + s_ * 2048); \
    } }

#define RDMM(SMp, b) { \
    const u16* as_ = SMp + (b) * 8192; \
    bf16x8 af[4], bfr[4]; \
    _Pragma("unroll") \
    for (int i = 0; i < 4; i++) af[i]  = *(const bf16x8*)&as_[(wm + i * 16 + r16) * 32 + ((quad ^ sw) * 8)]; \
    _Pragma("unroll") \
    for (int j = 0; j < 4; j++) bfr[j] = *(const bf16x8*)&as_[4096 + (wn + j * 16 + r16) * 32 + ((quad ^ sw) * 8)]; \
    __builtin_amdgcn_s_setprio(1); \
    _Pragma("unroll") \
    for (int i = 0; i < 4; i++) \
        _Pragma("unroll") \
        for (int j = 0; j < 4; j++) \
            acc[i][j] = MFMA(af[i], bfr[j], acc[i][j], 0, 0, 0); \
    __builtin_amdgcn_s_setprio(0); }

#define VMW4 asm volatile("s_waitcnt vmcnt(4)" ::: "memory")
#define VMW0 asm volatile("s_waitcnt vmcnt(0)" ::: "memory")
#define BAR  __builtin_amdgcn_s_barrier()

// ---------------- GEMM1: qkv = x @ w_attn + b_attn, scatter to q/k/v ----------------
__launch_bounds__(256)
__global__ void gemm_qkv(const u16* __restrict__ A, const u16* __restrict__ Bt,
                         const float* __restrict__ bias,
                         u16* __restrict__ q, u16* __restrict__ k, u16* __restrict__ v) {
    __shared__ __align__(16) u16 SM[24576];      // 3-buf staging 48KB; Cs overlays in epilogue
    u16 (*Cs)[132] = (u16(*)[132])SM;
    int tid = threadIdx.x;
    // XCD-slab swizzle: xcd = id&7 owns m-tiles xcd*8..+7 (A slab 1.6MB -> L2-resident)
    int id = blockIdx.x;
    int xcd = id & 7, jj = id >> 3;
    int m0 = (xcd * 8 + (jj & 7)) * 128;
    int n0 = (jj >> 3) * 128;
    int lane = tid & 63, wv = tid >> 6;
    int wm = (wv >> 1) * 64, wn = (wv & 1) * 64;
    int r16 = lane & 15, quad = lane >> 4;
    int sw = r16 & 3;

    f32x4 acc[4][4] = {};
    int sr = wv * 16 + (lane >> 2);              // staging row 0..63 (+64 for s=1)
    int scb = (lane & 3) ^ (sr & 3);             // pre-swizzled 16B col-block (row&3 inv. under +64)
    const u16* Ag = A  + (size_t)(m0 + sr) * C_ + scb * 8;
    const u16* Bg = Bt + (size_t)(n0 + sr) * C_ + scb * 8;
    u16* Ls = SM + wv * 512 + lane * 8;          // per-lane linear LDS staging ptr

    STG(Ag, Bg, Ls, 0, 0); STG(Ag, Bg, Ls, 1, 1);
    VMW4; BAR;                                    // kt0 landed everywhere; kt1 in flight

    for (int o = 0; o < 7; ++o) {                // kt = 3o .. 3o+2  (0..20), stages 2..22
        int kt = o * 3;
        STG(Ag, Bg, Ls, kt + 2, 2); RDMM(SM, 0); VMW4; BAR;
        STG(Ag, Bg, Ls, kt + 3, 0); RDMM(SM, 1); VMW4; BAR;
        STG(Ag, Bg, Ls, kt + 4, 1); RDMM(SM, 2); VMW4; BAR;
    }
    STG(Ag, Bg, Ls, 23, 2); RDMM(SM, 0); VMW4; BAR;   // kt=21 (stage 23 -> buf2)
    RDMM(SM, 1); VMW0; BAR;                            // kt=22 (kt23 fully landed)
    RDMM(SM, 2);                                       // kt=23

    __syncthreads();                             // reads drained before Cs overlay

    int sec = n0 / C_;                 // block-uniform: 0=q, 1=k, 2=v
    int cc0 = n0 - sec * C_;
    int b = m0 >> 10, t0 = m0 & 1023;

    if (sec == 2) {
        #pragma unroll
        for (int i = 0; i < 4; i++) {
            #pragma unroll
            for (int j = 0; j < 4; j++) {
                int cc = cc0 + wn + j * 16 + r16;
                float bv = bias[2 * C_ + cc];
                int h = cc >> 6, hd = cc & 63;
                int t = t0 + wm + i * 16 + quad * 4;
                ushort4 ov;
                ov.x = f2bf(acc[i][j][0] + bv); ov.y = f2bf(acc[i][j][1] + bv);
                ov.z = f2bf(acc[i][j][2] + bv); ov.w = f2bf(acc[i][j][3] + bv);
                *(ushort4*)(v + (((size_t)b * H_ + h) * HD_ + hd) * T_ + t) = ov;
            }
        }
    } else {
        float scale = (sec == 0) ? 0.125f : 1.0f;
        u16* dst = (sec == 0) ? q : k;
        #pragma unroll
        for (int i = 0; i < 4; i++)
            #pragma unroll
            for (int j = 0; j < 4; j++) {
                int col = wn + j * 16 + r16;
                float bv = bias[sec * C_ + cc0 + col];
                #pragma unroll
                for (int r = 0; r < 4; r++)
                    Cs[wm + i * 16 + quad * 4 + r][col] = f2bf((acc[i][j][r] + bv) * scale);
            }
        __syncthreads();
        int h0 = cc0 >> 6;
        int rsel = tid >> 4;
        int hs = (tid >> 3) & 1;
        int c8 = (tid & 7) * 8;
        #pragma unroll
        for (int p = 0; p < 8; p++) {
            int rl = p * 16 + rsel;
            uint4 val = *(const uint4*)&Cs[rl][hs * 64 + c8];
            *(uint4*)(dst + (((size_t)b * H_ + h0 + hs) * T_ + t0 + rl) * HD_ + c8) = val;
        }
    }
}

// ---------------- GEMM2: out = y @ w_proj + b_proj (fp32 out) ----------------
__launch_bounds__(256)
__global__ void gemm_proj(const u16* __restrict__ A, const u16* __restrict__ Bt,
                          const float* __restrict__ bias, float* __restrict__ out) {
    const int N = C_;
    __shared__ __align__(16) u16 SM[24576];      // 3-buf staging 48KB
    int tid = threadIdx.x;
    int id = blockIdx.x;
    int xcd = id & 7, jj = id >> 3;
    int m0 = (xcd * 8 + (jj & 7)) * 128;
    int n0 = (jj >> 3) * 128;
    int lane = tid & 63, wv = tid >> 6;
    int wm = (wv >> 1) * 64, wn = (wv & 1) * 64;
    int r16 = lane & 15, quad = lane >> 4;
    int sw = r16 & 3;

    f32x4 acc[4][4] = {};
    int sr = wv * 16 + (lane >> 2);
    int scb = (lane & 3) ^ (sr & 3);
    const u16* Ag = A  + (size_t)(m0 + sr) * C_ + scb * 8;
    const u16* Bg = Bt + (size_t)(n0 + sr) * C_ + scb * 8;
    u16* Ls = SM + wv * 512 + lane * 8;

    STG(Ag, Bg, Ls, 0, 0); STG(Ag, Bg, Ls, 1, 1);
    VMW4; BAR;

    for (int o = 0; o < 7; ++o) {
        int kt = o * 3;
        STG(Ag, Bg, Ls, kt + 2, 2); RDMM(SM, 0); VMW4; BAR;
        STG(Ag, Bg, Ls, kt + 3, 0); RDMM(SM, 1); VMW4; BAR;
        STG(Ag, Bg, Ls, kt + 4, 1); RDMM(SM, 2); VMW4; BAR;
    }
    STG(Ag, Bg, Ls, 23, 2); RDMM(SM, 0); VMW4; BAR;
    RDMM(SM, 1); VMW0; BAR;
    RDMM(SM, 2);

    #pragma unroll
    for (int i = 0; i < 4; i++) {
        #pragma unroll
        for (int j = 0; j < 4; j++) {
            int gn = n0 + wn + j * 16 + r16;
            float bv = bias[gn];
            #pragma unroll
            for (int r = 0; r < 4; r++) {
                int gm = m0 + wm + i * 16 + quad * 4 + r;
                out[(size_t)gm * N + gn] = acc[i][j][r] + bv;
            }
        }
    }
}

// ---------------- Flash attention: LDS-staged K/V (double-buffered), paired q-tiles ----
__launch_bounds__(256, 2)
__global__ void attn(const u16* __restrict__ q, const u16* __restrict__ k,
                     const u16* __restrict__ v, u16* __restrict__ y) {
    __shared__ __align__(16) u16 Kb[2][64][64];     // [buf][key][hd]
    __shared__ __align__(16) u16 Vb[2][64][64];     // [buf][hd][key]
    __shared__ __align__(16) u16 P[4][2][16][72];   // per-wave, per-tile P^T
    int tid = threadIdx.x, lane = tid & 63, w = tid >> 6;
    int r16 = lane & 15, quad = lane >> 4;
    int id = blockIdx.x;
    int bh = id % 96;             // same head -> ids 96 apart -> same XCD (96%8==0)
    int bi = id / 96;             // 0..7; bi=0 (longest, n64=16) dispatched first
    int b = bh / H_, h = bh - b * H_;
    int x = bi * 4 + w;           // 0..31
    int t_lo = x, t_hi = 63 - x;
    int qb_lo = t_lo * 16, qb_hi = t_hi * 16;
    const u16* qh = q + (size_t)bh * T_ * HD_;
    const u16* kh = k + (size_t)bh * T_ * HD_;
    const u16* vh = v + (size_t)bh * HD_ * T_;   // [HD][T]

    bf16x8 ql0 = *(const bf16x8*)(qh + (size_t)(qb_lo + r16) * HD_ + quad * 8);
    bf16x8 ql1 = *(const bf16x8*)(qh + (size_t)(qb_lo + r16) * HD_ + 32 + quad * 8);
    bf16x8 qh0 = *(const bf16x8*)(qh + (size_t)(qb_hi + r16) * HD_ + quad * 8);
    bf16x8 qh1 = *(const bf16x8*)(qh + (size_t)(qb_hi + r16) * HD_ + 32 + quad * 8);

    f32x4 oL[4] = {}, oH[4] = {};
    float lL = 0.f, lH = 0.f;
    int qyL = qb_lo + r16, qyH = qb_hi + r16;
    int ilo_last = bi;                                   // block-uniform
    int n64 = __builtin_amdgcn_readfirstlane(16 - bi);   // block-uniform

    int srow = lane >> 3;         // 0..7
    int scb  = (lane & 7) ^ srow; // XOR-swizzled global colblk
    const u16* kst = kh + (size_t)(w * 16 + srow) * HD_ + scb * 8;
    const u16* vst = vh + (size_t)(w * 16 + srow) * T_ + scb * 8;
    int swz = (r16 & 7);          // reader-side swizzle

    {
        #pragma unroll
        for (int s2 = 0; s2 < 2; s2++) {
            GLL16(kst + (size_t)(s2 * 8) * HD_, &Kb[0][w * 16 + s2 * 8][0] + lane * 8);
            GLL16(vst + (size_t)(s2 * 8) * T_,  &Vb[0][w * 16 + s2 * 8][0] + lane * 8);
        }
    }
    __syncthreads();

    for (int it = 0; it < n64; ++it) {
        int kv0 = it * 64;
        int buf = it & 1;
        bool lo_on = (it <= ilo_last);
        if (it + 1 < n64) {
            int kvn = kv0 + 64;
            #pragma unroll
            for (int s2 = 0; s2 < 2; s2++) {
                GLL16(kst + (size_t)(kvn + s2 * 8) * HD_, &Kb[buf ^ 1][w * 16 + s2 * 8][0] + lane * 8);
                GLL16(vst + (size_t)(s2 * 8) * T_ + kvn,  &Vb[buf ^ 1][w * 16 + s2 * 8][0] + lane * 8);
            }
        }
        bf16x8 kf[4][2];
        #pragma unroll
        for (int n = 0; n < 4; n++)
            #pragma unroll
            for (int c = 0; c < 2; c++)
                kf[n][c] = *(const bf16x8*)&Kb[buf][n * 16 + r16][((c * 4 + quad) ^ swz) * 8];
        f32x4 sH[4] = {};
        #pragma unroll
        for (int n = 0; n < 4; n++) {
            sH[n] = MFMA(kf[n][0], qh0, sH[n], 0, 0, 0);
            sH[n] = MFMA(kf[n][1], qh1, sH[n], 0, 0, 0);
        }
        if (it == n64 - 1) {
            #pragma unroll
            for (int n = 0; n < 4; n++)
                #pragma unroll
                for (int r = 0; r < 4; r++)
                    if (kv0 + n * 16 + quad * 4 + r > qyH) sH[n][r] = -1e30f;
        }
        #pragma unroll
        for (int n = 0; n < 4; n++) {
            float p0 = __expf(sH[n][0]);
            float p1 = __expf(sH[n][1]);
            float p2 = __expf(sH[n][2]);
            float p3 = __expf(sH[n][3]);
            lH += (p0 + p1) + (p2 + p3);
            uint2 pd; pd.x = pk2bf(p0, p1); pd.y = pk2bf(p2, p3);
            *(uint2*)&P[w][1][r16][n * 16 + quad * 4] = pd;
        }
        if (lo_on) {
            f32x4 sL[4] = {};
            #pragma unroll
            for (int n = 0; n < 4; n++) {
                sL[n] = MFMA(kf[n][0], ql0, sL[n], 0, 0, 0);
                sL[n] = MFMA(kf[n][1], ql1, sL[n], 0, 0, 0);
            }
            if (it == ilo_last) {
                #pragma unroll
                for (int n = 0; n < 4; n++)
                    #pragma unroll
                    for (int r = 0; r < 4; r++)
                        if (kv0 + n * 16 + quad * 4 + r > qyL) sL[n][r] = -1e30f;
            }
            #pragma unroll
            for (int n = 0; n < 4; n++) {
                float p0 = __expf(sL[n][0]);
                float p1 = __expf(sL[n][1]);
                float p2 = __expf(sL[n][2]);
                float p3 = __expf(sL[n][3]);
                lL += (p0 + p1) + (p2 + p3);
                uint2 pd; pd.x = pk2bf(p0, p1); pd.y = pk2bf(p2, p3);
                *(uint2*)&P[w][0][r16][n * 16 + quad * 4] = pd;
            }
        }
        bf16x8 vf[4][2];
        #pragma unroll
        for (int j = 0; j < 4; j++)
            #pragma unroll
            for (int c = 0; c < 2; c++)
                vf[j][c] = *(const bf16x8*)&Vb[buf][j * 16 + r16][((c * 4 + quad) ^ swz) * 8];
        #pragma unroll
        for (int c = 0; c < 2; c++) {
            bf16x8 pfH = *(const bf16x8*)&P[w][1][r16][c * 32 + quad * 8];
            #pragma unroll
            for (int j = 0; j < 4; j++)
                oH[j] = MFMA(vf[j][c], pfH, oH[j], 0, 0, 0);
        }
        if (lo_on) {
            #pragma unroll
            for (int c = 0; c < 2; c++) {
                bf16x8 pfL = *(const bf16x8*)&P[w][0][r16][c * 32 + quad * 8];
                #pragma unroll
                for (int j = 0; j < 4; j++)
                    oL[j] = MFMA(vf[j][c], pfL, oL[j], 0, 0, 0);
            }
        }
        __syncthreads();
    }

    lH += __shfl_xor(lH, 16, 64);
    lH += __shfl_xor(lH, 32, 64);
    lL += __shfl_xor(lL, 16, 64);
    lL += __shfl_xor(lL, 32, 64);
    float invH = 1.f / lH, invL = 1.f / lL;
    int tqH = qb_hi + r16, tqL = qb_lo + r16;
    #pragma unroll
    for (int j = 0; j < 4; j++) {
        ushort4 ovH, ovL;
        ovH.x = f2bf(oH[j][0] * invH); ovH.y = f2bf(oH[j][1] * invH);
        ovH.z = f2bf(oH[j][2] * invH); ovH.w = f2bf(oH[j][3] * invH);
        ovL.x = f2bf(oL[j][0] * invL); ovL.y = f2bf(oL[j][1] * invL);
        ovL.z = f2bf(oL[j][2] * invL); ovL.w = f2bf(oL[j][3] * invL);
        *(ushort4*)(y + ((size_t)b * T_ + tqH) * C_ + h * 64 + j * 16 + quad * 4) = ovH;
        *(ushort4*)(y + ((size_t)b * T_ + tqL) * C_ + h * 64 + j * 16 + quad * 4) = ovL;
    }
}

extern "C" void kernel_launch(void* const* d_in, const int* in_sizes, int n_in,
                              void* d_out, int out_size, void* d_ws, size_t ws_size,
                              hipStream_t stream) {
    const float* x      = (const float*)d_in[0];
    const float* w_attn = (const float*)d_in[1];
    const float* b_attn = (const float*)d_in[2];
    const float* w_proj = (const float*)d_in[3];
    const float* b_proj = (const float*)d_in[4];
    float* out = (float*)d_out;

    char* ws = (char*)d_ws;
    size_t off = 0;
    auto alloc = [&](size_t bytes) {
        void* p = ws + off;
        off += (bytes + 255) & ~(size_t)255;
        return p;
    };
    const size_t M = (size_t)B_ * T_;                    // 8192
    u16* x_bf = (u16*)alloc(M * C_ * 2);                 // [8192][768]
    u16* wat  = (u16*)alloc((size_t)K3_ * C_ * 2);       // [2304][768]
    u16* wpt  = (u16*)alloc((size_t)C_ * C_ * 2);        // [768][768]
    u16* qb   = (u16*)alloc((size_t)B_ * H_ * T_ * HD_ * 2);
    u16* kb   = (u16*)alloc((size_t)B_ * H_ * T_ * HD_ * 2);
    u16* vb   = (u16*)alloc((size_t)B_ * H_ * T_ * HD_ * 2);
    u16* yb   = (u16*)alloc(M * C_ * 2);                 // [8192][768]

    prep<<<6144 + 1728 + 576, 256, 0, stream>>>(x, x_bf, w_attn, wat, w_proj, wpt);
    gemm_qkv<<<8 * 144, 256, 0, stream>>>(x_bf, wat, b_attn, qb, kb, vb);
    attn<<<8 * 96, 256, 0, stream>>>(qb, kb, vb, yb);
    gemm_proj<<<8 * 48, 256, 0, stream>>>(yb, wpt, b_proj, out);
}

// Round 3
// 168.735 us; speedup vs baseline: 1.0442x; 1.0334x over previous
//
#include <hip/hip_runtime.h>
#include <cstdint>
#include <cstddef>

#define B_  8
#define T_  1024
#define C_  768
#define H_  12
#define HD_ 64
#define K3_ 2304   // 3*C

typedef unsigned short u16;
typedef __attribute__((ext_vector_type(8))) short bf16x8;   // 8 bf16 (4 VGPRs)
typedef __attribute__((ext_vector_type(4))) float f32x4;    // 4 fp32 acc

#define MFMA __builtin_amdgcn_mfma_f32_16x16x32_bf16

__device__ __forceinline__ u16 f2bf(float f) {
    unsigned u = __builtin_bit_cast(unsigned, f);
    u += 0x7fffu + ((u >> 16) & 1u);           // round-to-nearest-even
    return (u16)(u >> 16);
}

// pack two fp32 -> bf16x2 dword (round-half-up; P>=0, feeds bf16 MFMA)
__device__ __forceinline__ unsigned pk2bf(float a, float b) {
    unsigned ua = __builtin_bit_cast(unsigned, a) + 0x8000u;
    unsigned ub = __builtin_bit_cast(unsigned, b) + 0x8000u;
    return (ua >> 16) | (ub & 0xffff0000u);
}

// async global->LDS, 16 B per lane. LDS dest = wave-uniform base + lane*16.
#define GLL16(gp, lp) __builtin_amdgcn_global_load_lds( \
    (__attribute__((address_space(1))) unsigned int*)(gp), \
    (__attribute__((address_space(3))) unsigned int*)(lp), 16, 0, 0)

// ---------------- prep: x->bf16 + both weight transposes, one kernel ----------------
__device__ __forceinline__ void tcvt_tile(const float* __restrict__ in, u16* __restrict__ out,
                                          int R, int Cc, int bx, int by, int tid, float* tile /*32x33*/) {
    int bc = bx * 32, br = by * 32;
    int tx = tid & 31, ty = tid >> 5;   // (32, 8)
    #pragma unroll
    for (int kk = 0; kk < 32; kk += 8)
        tile[(ty + kk) * 33 + tx] = in[(size_t)(br + ty + kk) * Cc + bc + tx];
    __syncthreads();
    #pragma unroll
    for (int kk = 0; kk < 32; kk += 8)
        out[(size_t)(bc + ty + kk) * R + br + tx] = f2bf(tile[tx * 33 + ty + kk]);
}

__global__ void prep(const float* __restrict__ x, u16* __restrict__ xb,
                     const float* __restrict__ wa, u16* __restrict__ wat,
                     const float* __restrict__ wp, u16* __restrict__ wpt) {
    __shared__ float tile[32 * 33];
    int bid = blockIdx.x, tid = threadIdx.x;
    if (bid < 6144) {                      // cvt: 8192*768/4 elements of float4
        int i = bid * 256 + tid;
        float4 v = ((const float4*)x)[i];
        ushort4 o;
        o.x = f2bf(v.x); o.y = f2bf(v.y); o.z = f2bf(v.z); o.w = f2bf(v.w);
        ((ushort4*)xb)[i] = o;
    } else if (bid < 6144 + 1728) {        // w_attn [768][2304] -> [2304][768]
        int b = bid - 6144;
        tcvt_tile(wa, wat, C_, K3_, b % 72, b / 72, tid, tile);
    } else {                               // w_proj [768][768] -> [768][768]^T
        int b = bid - 7872;
        tcvt_tile(wp, wpt, C_, C_, b % 24, b / 24, tid, tile);
    }
}

// ============ phase-split pipelined GEMM core (T2+T3+T4+T5) ============
// BM=128, BN=256, BK=64, 8 waves (2M x 4N), per-wave 64x64 out (4x4 frags).
// LDS: 3-slot circular ring per matrix (A 3x16KB, B 3x32KB = 144KB).
// Iteration it processes K-tiles 2it (slot sa), 2it+1 (slot sb) in 4 phases
// of exactly 16 MFMA each: (sa,k0),(sa,k1),(sb,k0),(sb,k1).
// Stages: P1,P2 stage tile 2it+2 -> sc (3 units each); P3,P4 stage tile
// 2it+3 -> sa (freed at P2 end). vmcnt(6) ONLY at P2/P4 (never 0 in loop):
//   P2-wait drains tile 2it+1 (staged prev P3/P4) before P3 reads it;
//   P4-wait drains tile 2it+2 (staged this P1/P2) before next-iter P1.
// Every cross-wave RAW edge = (own vmcnt -> barrier); WAR edges = a slot is
// only staged after the phase-closing barrier of its last reader.
// Swizzle: rows are 64 bf16 = 128 B -> 3-bit XOR (blk ^= row&7), the
// round-0-verified conflict-free pattern (0 bank conflicts measured).
#define VMW6 asm volatile("s_waitcnt vmcnt(6)" ::: "memory")
#define VMW0 asm volatile("s_waitcnt vmcnt(0)" ::: "memory")
#define BAR  __builtin_amdgcn_s_barrier()

__device__ __forceinline__ void gemm_pipe(const u16* __restrict__ A, const u16* __restrict__ Bt,
                                          int m0, int n0, u16* SM, f32x4 (&acc)[4][4]) {
    const int K = C_;
    int tid = threadIdx.x;
    int lane = tid & 63, wv = tid >> 6;
    int wr = wv >> 2, wc = wv & 3;          // wave grid 2M x 4N
    int r16 = lane & 15, quad = lane >> 4;
    int sw = r16 & 7;
    int x0 = (quad ^ sw) * 8;               // kk=0 swizzled 16B block (u16 units)
    int x1 = ((4 + quad) ^ sw) * 8;         // kk=1
    int arow = (wr * 64 + r16) * 64;
    int brow = (wc * 64 + r16) * 64;
    // staging: thread t -> row t>>3, 16B-block (t&7) ^ (row&7); LDS linear t*16B
    int tr = tid >> 3;                      // 0..63
    int tb = (tid & 7) ^ (tr & 7);
    const u16* Ag = A  + (size_t)(m0 + tr) * K + tb * 8;
    const u16* Bg = Bt + (size_t)(n0 + tr) * K + tb * 8;
    u16* SLa = SM + tid * 8;
    u16* SLb = SM + 24576 + tid * 8;
    const u16* SMB = SM + 24576;

#define STG_A(ss, kO, u)  GLL16(Ag + (size_t)(u) * 64 * K + (kO), SLa + (ss) * 8192 + (u) * 4096)
#define STG_B(ss, kO, u)  GLL16(Bg + (size_t)(u) * 64 * K + (kO), SLb + (ss) * 16384 + (u) * 4096)
#define STG_H0(ss, kO) { STG_A(ss, kO, 0); STG_A(ss, kO, 1); STG_B(ss, kO, 0); }
#define STG_H1(ss, kO) { STG_B(ss, kO, 1); STG_B(ss, kO, 2); STG_B(ss, kO, 3); }
#define RD(rs, XC) { \
    const u16* Ar_ = SM  + (rs) * 8192  + arow; \
    const u16* Br_ = SMB + (rs) * 16384 + brow; \
    _Pragma("unroll") for (int i_ = 0; i_ < 4; i_++) af[i_] = *(const bf16x8*)&Ar_[i_ * 1024 + (XC)]; \
    _Pragma("unroll") for (int j_ = 0; j_ < 4; j_++) bb[j_] = *(const bf16x8*)&Br_[j_ * 1024 + (XC)]; }
#define MM() { \
    __builtin_amdgcn_s_setprio(1); \
    _Pragma("unroll") for (int i_ = 0; i_ < 4; i_++) \
    _Pragma("unroll") for (int j_ = 0; j_ < 4; j_++) \
        acc[i_][j_] = MFMA(af[i_], bb[j_], acc[i_][j_], 0, 0, 0); \
    __builtin_amdgcn_s_setprio(0); }

    // prologue: tile0 -> slot0, tile1 -> slot1 (12 units); wait tile0 (6 left)
    STG_H0(0, 0);  STG_H1(0, 0);
    STG_H0(1, 64); STG_H1(1, 64);
    VMW6; BAR;

    int sa = 0, sb = 1, sc = 2;
    int kS = 128;                            // K-offset of tile 2it+2
    for (int it = 0; it < 5; ++it) {
        bf16x8 af[4], bb[4];
        RD(sa, x0); STG_H0(sc, kS);            BAR; MM(); BAR;   // P1
        RD(sa, x1); STG_H1(sc, kS);      VMW6; BAR; MM(); BAR;   // P2
        RD(sb, x0); STG_H0(sa, kS + 64);       BAR; MM(); BAR;   // P3
        RD(sb, x1); STG_H1(sa, kS + 64); VMW6; BAR; MM(); BAR;   // P4
        int t_ = sa; sa = sc; sc = sb; sb = t_;  // (sa,sb,sc) <- (sc,sa,sb)
        kS += 128;
    }
    // last iteration (tiles 10,11): no stages; vmcnt(0)+barrier makes ALL
    // waves' tile-11 stages visible before the final two reads.
    {
        bf16x8 af[4], bb[4];
        RD(sa, x0); MM();
        RD(sa, x1); MM();
        VMW0; BAR;
        RD(sb, x0); MM();
        RD(sb, x1); MM();
    }
#undef STG_A
#undef STG_B
#undef STG_H0
#undef STG_H1
#undef RD
#undef MM
}

// ---------------- GEMM1: qkv = x @ w_attn + b_attn, scatter to q/k/v ----------------
__launch_bounds__(512)
__global__ void gemm_qkv(const u16* __restrict__ A, const u16* __restrict__ Bt,
                         const float* __restrict__ bias,
                         u16* __restrict__ q, u16* __restrict__ k, u16* __restrict__ v) {
    __shared__ __align__(16) u16 SM[73728];      // 144KB ring; Cs overlays in epilogue
    int id = blockIdx.x;                          // 576 = 8 xcd * (8 m x 9 n)
    int xcd = id & 7, j = id >> 3;
    int m0 = (xcd * 8 + (j & 7)) * 128;           // XCD owns contiguous 8-tile A slab
    int n0 = (j >> 3) * 256;
    f32x4 acc[4][4] = {};
    gemm_pipe(A, Bt, m0, n0, SM, acc);

    int tid = threadIdx.x;
    int lane = tid & 63, wv = tid >> 6;
    int wr = wv >> 2, wc = wv & 3;
    int r16 = lane & 15, quad = lane >> 4;
    __syncthreads();

    int sec = n0 / C_;                 // block-uniform: 0=q, 1=k, 2=v (256 | 768)
    int cc0 = n0 - sec * C_;           // 0,256,512
    int b = m0 >> 10, t0 = m0 & 1023;

    if (sec == 2) {
        #pragma unroll
        for (int i = 0; i < 4; i++) {
            #pragma unroll
            for (int jj = 0; jj < 4; jj++) {
                int cc = cc0 + wc * 64 + jj * 16 + r16;
                float bv = bias[2 * C_ + cc];
                int h = cc >> 6, hd = cc & 63;
                int t = t0 + wr * 64 + i * 16 + quad * 4;
                ushort4 ov;
                ov.x = f2bf(acc[i][jj][0] + bv); ov.y = f2bf(acc[i][jj][1] + bv);
                ov.z = f2bf(acc[i][jj][2] + bv); ov.w = f2bf(acc[i][jj][3] + bv);
                *(ushort4*)(v + (((size_t)b * H_ + h) * HD_ + hd) * T_ + t) = ov;
            }
        }
    } else {
        float scale = (sec == 0) ? 0.125f : 1.0f;
        u16* dst = (sec == 0) ? q : k;
        u16 (*Cs)[136] = (u16(*)[136])SM;          // 128x136 (272B rows: 16B-aligned, bank-shift 4)
        #pragma unroll
        for (int half = 0; half < 2; half++) {     // 128 cols at a time through LDS
            if ((wc >> 1) == half) {
                #pragma unroll
                for (int i = 0; i < 4; i++)
                    #pragma unroll
                    for (int jj = 0; jj < 4; jj++) {
                        int col = (wc & 1) * 64 + jj * 16 + r16;
                        float bv = bias[sec * C_ + cc0 + half * 128 + col];
                        #pragma unroll
                        for (int r = 0; r < 4; r++)
                            Cs[wr * 64 + i * 16 + quad * 4 + r][col] = f2bf((acc[i][jj][r] + bv) * scale);
                    }
            }
            __syncthreads();
            int rsel = tid >> 4;                   // 0..31
            int ch = tid & 15;                     // 16B chunk within 128 cols
            int hh = (cc0 + half * 128 + ch * 8) >> 6;
            int hd0 = (ch & 7) * 8;
            #pragma unroll
            for (int p = 0; p < 4; p++) {
                int rl = p * 32 + rsel;
                uint4 val = *(const uint4*)&Cs[rl][ch * 8];
                *(uint4*)(dst + (((size_t)b * H_ + hh) * T_ + t0 + rl) * HD_ + hd0) = val;
            }
            __syncthreads();
        }
    }
}

// ---------------- GEMM2: out = y @ w_proj + b_proj (fp32 out) ----------------
__launch_bounds__(512)
__global__ void gemm_proj(const u16* __restrict__ A, const u16* __restrict__ Bt,
                          const float* __restrict__ bias, float* __restrict__ out) {
    __shared__ __align__(16) u16 SM[73728];
    int id = blockIdx.x;                          // 192 = 8 xcd * (8 m x 3 n)
    int xcd = id & 7, j = id >> 3;
    int m0 = (xcd * 8 + (j & 7)) * 128;
    int n0 = (j >> 3) * 256;
    f32x4 acc[4][4] = {};
    gemm_pipe(A, Bt, m0, n0, SM, acc);

    int tid = threadIdx.x;
    int lane = tid & 63, wv = tid >> 6;
    int wr = wv >> 2, wc = wv & 3;
    int r16 = lane & 15, quad = lane >> 4;
    #pragma unroll
    for (int i = 0; i < 4; i++) {
        #pragma unroll
        for (int jj = 0; jj < 4; jj++) {
            int gn = n0 + wc * 64 + jj * 16 + r16;
            float bv = bias[gn];
            #pragma unroll
            for (int r = 0; r < 4; r++) {
                int gm = m0 + wr * 64 + i * 16 + quad * 4 + r;
                out[(size_t)gm * C_ + gn] = acc[i][jj][r] + bv;
            }
        }
    }
}

// ---------------- Flash attention: LDS-staged K/V (double-buffered), paired q-tiles ----
__launch_bounds__(256, 2)
__global__ void attn(const u16* __restrict__ q, const u16* __restrict__ k,
                     const u16* __restrict__ v, u16* __restrict__ y) {
    __shared__ __align__(16) u16 Kb[2][64][64];     // [buf][key][hd]
    __shared__ __align__(16) u16 Vb[2][64][64];     // [buf][hd][key]
    __shared__ __align__(16) u16 P[4][2][16][72];   // per-wave, per-tile P^T
    int tid = threadIdx.x, lane = tid & 63, w = tid >> 6;
    int r16 = lane & 15, quad = lane >> 4;
    int id = blockIdx.x;
    int bh = id % 96;             // same head -> ids 96 apart -> same XCD (96%8==0)
    int bi = id / 96;             // 0..7; bi=0 (longest, n64=16) dispatched first
    int b = bh / H_, h = bh - b * H_;
    int x = bi * 4 + w;           // 0..31
    int t_lo = x, t_hi = 63 - x;
    int qb_lo = t_lo * 16, qb_hi = t_hi * 16;
    const u16* qh = q + (size_t)bh * T_ * HD_;
    const u16* kh = k + (size_t)bh * T_ * HD_;
    const u16* vh = v + (size_t)bh * HD_ * T_;   // [HD][T]

    bf16x8 ql0 = *(const bf16x8*)(qh + (size_t)(qb_lo + r16) * HD_ + quad * 8);
    bf16x8 ql1 = *(const bf16x8*)(qh + (size_t)(qb_lo + r16) * HD_ + 32 + quad * 8);
    bf16x8 qh0 = *(const bf16x8*)(qh + (size_t)(qb_hi + r16) * HD_ + quad * 8);
    bf16x8 qh1 = *(const bf16x8*)(qh + (size_t)(qb_hi + r16) * HD_ + 32 + quad * 8);

    f32x4 oL[4] = {}, oH[4] = {};
    float lL = 0.f, lH = 0.f;
    int qyL = qb_lo + r16, qyH = qb_hi + r16;
    int ilo_last = bi;                                   // block-uniform
    int n64 = __builtin_amdgcn_readfirstlane(16 - bi);   // block-uniform

    int srow = lane >> 3;         // 0..7
    int scb  = (lane & 7) ^ srow; // XOR-swizzled global colblk
    const u16* kst = kh + (size_t)(w * 16 + srow) * HD_ + scb * 8;
    const u16* vst = vh + (size_t)(w * 16 + srow) * T_ + scb * 8;
    int swz = (r16 & 7);          // reader-side swizzle

    {
        #pragma unroll
        for (int s2 = 0; s2 < 2; s2++) {
            GLL16(kst + (size_t)(s2 * 8) * HD_, &Kb[0][w * 16 + s2 * 8][0] + lane * 8);
            GLL16(vst + (size_t)(s2 * 8) * T_,  &Vb[0][w * 16 + s2 * 8][0] + lane * 8);
        }
    }
    __syncthreads();

    for (int it = 0; it < n64; ++it) {
        int kv0 = it * 64;
        int buf = it & 1;
        bool lo_on = (it <= ilo_last);
        if (it + 1 < n64) {
            int kvn = kv0 + 64;
            #pragma unroll
            for (int s2 = 0; s2 < 2; s2++) {
                GLL16(kst + (size_t)(kvn + s2 * 8) * HD_, &Kb[buf ^ 1][w * 16 + s2 * 8][0] + lane * 8);
                GLL16(vst + (size_t)(s2 * 8) * T_ + kvn,  &Vb[buf ^ 1][w * 16 + s2 * 8][0] + lane * 8);
            }
        }
        bf16x8 kf[4][2];
        #pragma unroll
        for (int n = 0; n < 4; n++)
            #pragma unroll
            for (int c = 0; c < 2; c++)
                kf[n][c] = *(const bf16x8*)&Kb[buf][n * 16 + r16][((c * 4 + quad) ^ swz) * 8];
        f32x4 sH[4] = {};
        #pragma unroll
        for (int n = 0; n < 4; n++) {
            sH[n] = MFMA(kf[n][0], qh0, sH[n], 0, 0, 0);
            sH[n] = MFMA(kf[n][1], qh1, sH[n], 0, 0, 0);
        }
        if (it == n64 - 1) {
            #pragma unroll
            for (int n = 0; n < 4; n++)
                #pragma unroll
                for (int r = 0; r < 4; r++)
                    if (kv0 + n * 16 + quad * 4 + r > qyH) sH[n][r] = -1e30f;
        }
        #pragma unroll
        for (int n = 0; n < 4; n++) {
            float p0 = __expf(sH[n][0]);
            float p1 = __expf(sH[n][1]);
            float p2 = __expf(sH[n][2]);
            float p3 = __expf(sH[n][3]);
            lH += (p0 + p1) + (p2 + p3);
            uint2 pd; pd.x = pk2bf(p0, p1); pd.y = pk2bf(p2, p3);
            *(uint2*)&P[w][1][r16][n * 16 + quad * 4] = pd;
        }
        if (lo_on) {
            f32x4 sL[4] = {};
            #pragma unroll
            for (int n = 0; n < 4; n++) {
                sL[n] = MFMA(kf[n][0], ql0, sL[n], 0, 0, 0);
                sL[n] = MFMA(kf[n][1], ql1, sL[n], 0, 0, 0);
            }
            if (it == ilo_last) {
                #pragma unroll
                for (int n = 0; n < 4; n++)
                    #pragma unroll
                    for (int r = 0; r < 4; r++)
                        if (kv0 + n * 16 + quad * 4 + r > qyL) sL[n][r] = -1e30f;
            }
            #pragma unroll
            for (int n = 0; n < 4; n++) {
                float p0 = __expf(sL[n][0]);
                float p1 = __expf(sL[n][1]);
                float p2 = __expf(sL[n][2]);
                float p3 = __expf(sL[n][3]);
                lL += (p0 + p1) + (p2 + p3);
                uint2 pd; pd.x = pk2bf(p0, p1); pd.y = pk2bf(p2, p3);
                *(uint2*)&P[w][0][r16][n * 16 + quad * 4] = pd;
            }
        }
        bf16x8 vf[4][2];
        #pragma unroll
        for (int j = 0; j < 4; j++)
            #pragma unroll
            for (int c = 0; c < 2; c++)
                vf[j][c] = *(const bf16x8*)&Vb[buf][j * 16 + r16][((c * 4 + quad) ^ swz) * 8];
        #pragma unroll
        for (int c = 0; c < 2; c++) {
            bf16x8 pfH = *(const bf16x8*)&P[w][1][r16][c * 32 + quad * 8];
            #pragma unroll
            for (int j = 0; j < 4; j++)
                oH[j] = MFMA(vf[j][c], pfH, oH[j], 0, 0, 0);
        }
        if (lo_on) {
            #pragma unroll
            for (int c = 0; c < 2; c++) {
                bf16x8 pfL = *(const bf16x8*)&P[w][0][r16][c * 32 + quad * 8];
                #pragma unroll
                for (int j = 0; j < 4; j++)
                    oL[j] = MFMA(vf[j][c], pfL, oL[j], 0, 0, 0);
            }
        }
        __syncthreads();
    }

    lH += __shfl_xor(lH, 16, 64);
    lH += __shfl_xor(lH, 32, 64);
    lL += __shfl_xor(lL, 16, 64);
    lL += __shfl_xor(lL, 32, 64);
    float invH = 1.f / lH, invL = 1.f / lL;
    int tqH = qb_hi + r16, tqL = qb_lo + r16;
    #pragma unroll
    for (int j = 0; j < 4; j++) {
        ushort4 ovH, ovL;
        ovH.x = f2bf(oH[j][0] * invH); ovH.y = f2bf(oH[j][1] * invH);
        ovH.z = f2bf(oH[j][2] * invH); ovH.w = f2bf(oH[j][3] * invH);
        ovL.x = f2bf(oL[j][0] * invL); ovL.y = f2bf(oL[j][1] * invL);
        ovL.z = f2bf(oL[j][2] * invL); ovL.w = f2bf(oL[j][3] * invL);
        *(ushort4*)(y + ((size_t)b * T_ + tqH) * C_ + h * 64 + j * 16 + quad * 4) = ovH;
        *(ushort4*)(y + ((size_t)b * T_ + tqL) * C_ + h * 64 + j * 16 + quad * 4) = ovL;
    }
}

extern "C" void kernel_launch(void* const* d_in, const int* in_sizes, int n_in,
                              void* d_out, int out_size, void* d_ws, size_t ws_size,
                              hipStream_t stream) {
    const float* x      = (const float*)d_in[0];
    const float* w_attn = (const float*)d_in[1];
    const float* b_attn = (const float*)d_in[2];
    const float* w_proj = (const float*)d_in[3];
    const float* b_proj = (const float*)d_in[4];
    float* out = (float*)d_out;

    char* ws = (char*)d_ws;
    size_t off = 0;
    auto alloc = [&](size_t bytes) {
        void* p = ws + off;
        off += (bytes + 255) & ~(size_t)255;
        return p;
    };
    const size_t M = (size_t)B_ * T_;                    // 8192
    u16* x_bf = (u16*)alloc(M * C_ * 2);                 // [8192][768]
    u16* wat  = (u16*)alloc((size_t)K3_ * C_ * 2);       // [2304][768]
    u16* wpt  = (u16*)alloc((size_t)C_ * C_ * 2);        // [768][768]
    u16* qb   = (u16*)alloc((size_t)B_ * H_ * T_ * HD_ * 2);
    u16* kb   = (u16*)alloc((size_t)B_ * H_ * T_ * HD_ * 2);
    u16* vb   = (u16*)alloc((size_t)B_ * H_ * T_ * HD_ * 2);
    u16* yb   = (u16*)alloc(M * C_ * 2);                 // [8192][768]

    prep<<<6144 + 1728 + 576, 256, 0, stream>>>(x, x_bf, w_attn, wat, w_proj, wpt);
    gemm_qkv<<<576, 512, 0, stream>>>(x_bf, wat, b_attn, qb, kb, vb);
    attn<<<8 * 96, 256, 0, stream>>>(qb, kb, vb, yb);
    gemm_proj<<<192, 512, 0, stream>>>(yb, wpt, b_proj, out);
}

// Round 4
// 155.516 us; speedup vs baseline: 1.1329x; 1.0850x over previous
//
#include <hip/hip_runtime.h>
#include <cstdint>
#include <cstddef>

#define B_  8
#define T_  1024
#define C_  768
#define H_  12
#define HD_ 64
#define K3_ 2304   // 3*C

typedef unsigned short u16;
typedef __attribute__((ext_vector_type(8))) short bf16x8;   // 8 bf16 (4 VGPRs)
typedef __attribute__((ext_vector_type(4))) float f32x4;    // 4 fp32 acc

#define MFMA __builtin_amdgcn_mfma_f32_16x16x32_bf16

__device__ __forceinline__ u16 f2bf(float f) {
    unsigned u = __builtin_bit_cast(unsigned, f);
    u += 0x7fffu + ((u >> 16) & 1u);           // round-to-nearest-even
    return (u16)(u >> 16);
}

// pack two fp32 -> bf16x2 dword (round-half-up; P>=0, feeds bf16 MFMA)
__device__ __forceinline__ unsigned pk2bf(float a, float b) {
    unsigned ua = __builtin_bit_cast(unsigned, a) + 0x8000u;
    unsigned ub = __builtin_bit_cast(unsigned, b) + 0x8000u;
    return (ua >> 16) | (ub & 0xffff0000u);
}

// async global->LDS, 16 B per lane. LDS dest = wave-uniform base + lane*16.
#define GLL16(gp, lp) __builtin_amdgcn_global_load_lds( \
    (__attribute__((address_space(1))) unsigned int*)(gp), \
    (__attribute__((address_space(3))) unsigned int*)(lp), 16, 0, 0)

// ---------------- prep: x->bf16 + both weight transposes, one kernel ----------------
__device__ __forceinline__ void tcvt_tile(const float* __restrict__ in, u16* __restrict__ out,
                                          int R, int Cc, int bx, int by, int tid, float* tile /*32x33*/) {
    int bc = bx * 32, br = by * 32;
    int tx = tid & 31, ty = tid >> 5;   // (32, 8)
    #pragma unroll
    for (int kk = 0; kk < 32; kk += 8)
        tile[(ty + kk) * 33 + tx] = in[(size_t)(br + ty + kk) * Cc + bc + tx];
    __syncthreads();
    #pragma unroll
    for (int kk = 0; kk < 32; kk += 8)
        out[(size_t)(bc + ty + kk) * R + br + tx] = f2bf(tile[tx * 33 + ty + kk]);
}

__global__ void prep(const float* __restrict__ x, u16* __restrict__ xb,
                     const float* __restrict__ wa, u16* __restrict__ wat,
                     const float* __restrict__ wp, u16* __restrict__ wpt) {
    __shared__ float tile[32 * 33];
    int bid = blockIdx.x, tid = threadIdx.x;
    if (bid < 6144) {                      // cvt: 8192*768/4 elements of float4
        int i = bid * 256 + tid;
        float4 v = ((const float4*)x)[i];
        ushort4 o;
        o.x = f2bf(v.x); o.y = f2bf(v.y); o.z = f2bf(v.z); o.w = f2bf(v.w);
        ((ushort4*)xb)[i] = o;
    } else if (bid < 6144 + 1728) {        // w_attn [768][2304] -> [2304][768]
        int b = bid - 6144;
        tcvt_tile(wa, wat, C_, K3_, b % 72, b / 72, tid, tile);
    } else {                               // w_proj [768][768] -> [768][768]^T
        int b = bid - 7872;
        tcvt_tile(wp, wpt, C_, C_, b % 24, b / 24, tid, tile);
    }
}

// ============ phase-split pipelined GEMM core (T2+T3+T4+T5) ============
// BM=128, BN=192, BK=64, 8 waves (2M x 4N), per-wave 64x48 out (4x3 frags).
// LDS: 3-slot ring (A 3x16KB + B 3x24KB = 120KB). Grid sized to FULL CU
// rounds (qkv 768 = 3 rounds, proj 256 = 1 round; 1 block/CU at 120KB).
// ONE phase per K-tile: {14 ds_read, stage tile kt+2 (5 loads), 24 MFMA,
// vmcnt(5), s_barrier}. Ledger: enter kt with 5 outstanding (tile kt+1);
// +5 -> 10; vmcnt(5) drains tile kt+1 (ready for next phase); never 0 in
// loop. WAR: stage targets slot (kt+2)%3=(kt-1)%3 whose readers' MFMAs
// (lgkm-waited) completed before the kt-1 barrier -> one barrier suffices.
// Swizzle: 128B rows, 3-bit XOR chunk^(row&7) both sides (round-0-verified
// conflict-free).
#define VMW5 asm volatile("s_waitcnt vmcnt(5)" ::: "memory")
#define VMW0 asm volatile("s_waitcnt vmcnt(0)" ::: "memory")
#define BAR  __builtin_amdgcn_s_barrier()

__device__ __forceinline__ void gemm_pipe(const u16* __restrict__ A, const u16* __restrict__ Bt,
                                          int m0, int n0, u16* SM, f32x4 (&acc)[4][3]) {
    const int K = C_;
    int tid = threadIdx.x;
    int lane = tid & 63, wv = tid >> 6;
    int wr = wv >> 2, wc = wv & 3;          // wave grid 2M x 4N
    int r16 = lane & 15, quad = lane >> 4;
    int sw = r16 & 7;
    int x0 = (quad ^ sw) * 8;               // kk=0 swizzled 16B block (u16 units)
    int x1 = ((4 + quad) ^ sw) * 8;         // kk=1
    int arow = (wr * 64 + r16) * 64;
    int brow = (wc * 48 + r16) * 64;
    // staging: thread t -> row t>>3 (+64 per unit), chunk (t&7)^(row&7); LDS linear t*16B
    int tr = tid >> 3;                      // 0..63
    int tb = (tid & 7) ^ (tr & 7);
    const u16* Ag = A  + (size_t)(m0 + tr) * K + tb * 8;
    const u16* Bg = Bt + (size_t)(n0 + tr) * K + tb * 8;
    u16* SLa = SM + tid * 8;
    u16* SLb = SM + 24576 + tid * 8;
    const u16* SMB = SM + 24576;

#define STG_T(ss, kO) { \
    GLL16(Ag + (kO),                       SLa + (ss) * 8192); \
    GLL16(Ag + (size_t)64 * K + (kO),      SLa + (ss) * 8192 + 4096); \
    GLL16(Bg + (kO),                       SLb + (ss) * 12288); \
    GLL16(Bg + (size_t)64 * K + (kO),      SLb + (ss) * 12288 + 4096); \
    GLL16(Bg + (size_t)128 * K + (kO),     SLb + (ss) * 12288 + 8192); }
#define RDH(rs, XC, af, bf) { \
    const u16* Ar_ = SM  + (rs) * 8192  + arow; \
    const u16* Br_ = SMB + (rs) * 12288 + brow; \
    _Pragma("unroll") for (int i_ = 0; i_ < 4; i_++) af[i_] = *(const bf16x8*)&Ar_[i_ * 1024 + (XC)]; \
    _Pragma("unroll") for (int j_ = 0; j_ < 3; j_++) bf[j_] = *(const bf16x8*)&Br_[j_ * 1024 + (XC)]; }
#define MMH(af, bf) { \
    __builtin_amdgcn_s_setprio(1); \
    _Pragma("unroll") for (int i_ = 0; i_ < 4; i_++) \
    _Pragma("unroll") for (int j_ = 0; j_ < 3; j_++) \
        acc[i_][j_] = MFMA(af[i_], bf[j_], acc[i_][j_], 0, 0, 0); \
    __builtin_amdgcn_s_setprio(0); }
#define PHASE(rs, ts, kO) { \
    bf16x8 a0[4], b0[3], a1[4], b1[3]; \
    RDH(rs, x0, a0, b0); RDH(rs, x1, a1, b1); \
    STG_T(ts, kO); \
    MMH(a0, b0); MMH(a1, b1); \
    VMW5; BAR; }

    // prologue: tile0 -> slot0, tile1 -> slot1 (10 loads); drain tile0 (5 left)
    STG_T(0, 0); STG_T(1, 64);
    VMW5; BAR;

    int kS = 128;                            // K-offset of tile kt+2
    #pragma unroll
    for (int o = 0; o < 3; ++o) {            // kt = 3o..3o+2  (0..8)
        PHASE(0, 2, kS);
        PHASE(1, 0, kS + 64);
        PHASE(2, 1, kS + 128);
        kS += 192;
    }
    PHASE(0, 2, 704);                        // kt=9, stages tile 11
    {                                        // kt=10: drain tile 11 fully
        bf16x8 a0[4], b0[3], a1[4], b1[3];
        RDH(1, x0, a0, b0); RDH(1, x1, a1, b1);
        MMH(a0, b0); MMH(a1, b1);
        VMW0; BAR;
    }
    {                                        // kt=11
        bf16x8 a0[4], b0[3], a1[4], b1[3];
        RDH(2, x0, a0, b0); RDH(2, x1, a1, b1);
        MMH(a0, b0); MMH(a1, b1);
    }
#undef STG_T
#undef RDH
#undef MMH
#undef PHASE
}

// ---------------- GEMM1: qkv = x @ w_attn + b_attn, scatter to q/k/v ----------------
__launch_bounds__(512)
__global__ void gemm_qkv(const u16* __restrict__ A, const u16* __restrict__ Bt,
                         const float* __restrict__ bias,
                         u16* __restrict__ q, u16* __restrict__ k, u16* __restrict__ v) {
    __shared__ __align__(16) u16 SM[61440];      // 120KB ring; Cs overlays in epilogue
    int id = blockIdx.x;                          // 768 = 8 xcd * (8 m x 12 n)
    int xcd = id & 7, j = id >> 3;
    int m0 = (xcd * 8 + (j & 7)) * 128;           // XCD owns contiguous 8-tile A slab
    int np = j >> 3;                              // n-panel 0..11 (192 cols each)
    f32x4 acc[4][3] = {};
    gemm_pipe(A, Bt, m0, np * 192, SM, acc);

    int tid = threadIdx.x;
    int lane = tid & 63, wv = tid >> 6;
    int wr = wv >> 2, wc = wv & 3;
    int r16 = lane & 15, quad = lane >> 4;
    __syncthreads();                              // all LDS reads drained before overlay

    int sec = np >> 2;                 // block-uniform: 0=q, 1=k, 2=v
    int cc0 = (np & 3) * 192;          // col offset within section (3 heads/panel)
    int b = m0 >> 10, t0 = m0 & 1023;

    if (sec == 2) {
        #pragma unroll
        for (int i = 0; i < 4; i++) {
            #pragma unroll
            for (int jj = 0; jj < 3; jj++) {
                int cc = cc0 + wc * 48 + jj * 16 + r16;
                float bv = bias[2 * C_ + cc];
                int h = cc >> 6, hd = cc & 63;
                int t = t0 + wr * 64 + i * 16 + quad * 4;
                ushort4 ov;
                ov.x = f2bf(acc[i][jj][0] + bv); ov.y = f2bf(acc[i][jj][1] + bv);
                ov.z = f2bf(acc[i][jj][2] + bv); ov.w = f2bf(acc[i][jj][3] + bv);
                *(ushort4*)(v + (((size_t)b * H_ + h) * HD_ + hd) * T_ + t) = ov;
            }
        }
    } else {
        float scale = (sec == 0) ? 0.125f : 1.0f;
        u16* dst = (sec == 0) ? q : k;
        u16 (*Cs)[200] = (u16(*)[200])SM;          // 128x200 (400B rows, 16B-aligned)
        #pragma unroll
        for (int i = 0; i < 4; i++)
            #pragma unroll
            for (int jj = 0; jj < 3; jj++) {
                int col = wc * 48 + jj * 16 + r16;
                float bv = bias[sec * C_ + cc0 + col];
                #pragma unroll
                for (int r = 0; r < 4; r++)
                    Cs[wr * 64 + i * 16 + quad * 4 + r][col] = f2bf((acc[i][jj][r] + bv) * scale);
            }
        __syncthreads();
        int h0 = cc0 >> 6;                         // first of 3 heads in this panel
        int rsel = tid >> 3;                       // 0..63
        int ch = tid & 7;                          // 16B chunk within a head's 64 cols
        #pragma unroll
        for (int p = 0; p < 2; p++)
            #pragma unroll
            for (int h3 = 0; h3 < 3; h3++) {
                int rl = p * 64 + rsel;
                uint4 val = *(const uint4*)&Cs[rl][h3 * 64 + ch * 8];
                *(uint4*)(dst + (((size_t)b * H_ + h0 + h3) * T_ + t0 + rl) * HD_ + ch * 8) = val;
            }
    }
}

// ---------------- GEMM2: out = y @ w_proj + b_proj (fp32 out) ----------------
__launch_bounds__(512)
__global__ void gemm_proj(const u16* __restrict__ A, const u16* __restrict__ Bt,
                          const float* __restrict__ bias, float* __restrict__ out) {
    __shared__ __align__(16) u16 SM[61440];
    int id = blockIdx.x;                          // 256 = 8 xcd * (8 m x 4 n) -> 1 full round
    int xcd = id & 7, j = id >> 3;
    int m0 = (xcd * 8 + (j & 7)) * 128;
    int n0 = (j >> 3) * 192;
    f32x4 acc[4][3] = {};
    gemm_pipe(A, Bt, m0, n0, SM, acc);

    int tid = threadIdx.x;
    int lane = tid & 63, wv = tid >> 6;
    int wr = wv >> 2, wc = wv & 3;
    int r16 = lane & 15, quad = lane >> 4;
    #pragma unroll
    for (int i = 0; i < 4; i++) {
        #pragma unroll
        for (int jj = 0; jj < 3; jj++) {
            int gn = n0 + wc * 48 + jj * 16 + r16;
            float bv = bias[gn];
            #pragma unroll
            for (int r = 0; r < 4; r++) {
                int gm = m0 + wr * 64 + i * 16 + quad * 4 + r;
                out[(size_t)gm * C_ + gn] = acc[i][jj][r] + bv;
            }
        }
    }
}

// ---------------- Flash attention: LDS-staged K/V (double-buffered), paired q-tiles ----
__launch_bounds__(256, 2)
__global__ void attn(const u16* __restrict__ q, const u16* __restrict__ k,
                     const u16* __restrict__ v, u16* __restrict__ y) {
    __shared__ __align__(16) u16 Kb[2][64][64];     // [buf][key][hd]
    __shared__ __align__(16) u16 Vb[2][64][64];     // [buf][hd][key]
    __shared__ __align__(16) u16 P[4][2][16][72];   // per-wave, per-tile P^T
    int tid = threadIdx.x, lane = tid & 63, w = tid >> 6;
    int r16 = lane & 15, quad = lane >> 4;
    int id = blockIdx.x;
    int bh = id % 96;             // same head -> ids 96 apart -> same XCD (96%8==0)
    int bi = id / 96;             // 0..7; bi=0 (longest, n64=16) dispatched first
    int b = bh / H_, h = bh - b * H_;
    int x = bi * 4 + w;           // 0..31
    int t_lo = x, t_hi = 63 - x;
    int qb_lo = t_lo * 16, qb_hi = t_hi * 16;
    const u16* qh = q + (size_t)bh * T_ * HD_;
    const u16* kh = k + (size_t)bh * T_ * HD_;
    const u16* vh = v + (size_t)bh * HD_ * T_;   // [HD][T]

    bf16x8 ql0 = *(const bf16x8*)(qh + (size_t)(qb_lo + r16) * HD_ + quad * 8);
    bf16x8 ql1 = *(const bf16x8*)(qh + (size_t)(qb_lo + r16) * HD_ + 32 + quad * 8);
    bf16x8 qh0 = *(const bf16x8*)(qh + (size_t)(qb_hi + r16) * HD_ + quad * 8);
    bf16x8 qh1 = *(const bf16x8*)(qh + (size_t)(qb_hi + r16) * HD_ + 32 + quad * 8);

    f32x4 oL[4] = {}, oH[4] = {};
    float lL = 0.f, lH = 0.f;
    int qyL = qb_lo + r16, qyH = qb_hi + r16;
    int ilo_last = bi;                                   // block-uniform
    int n64 = __builtin_amdgcn_readfirstlane(16 - bi);   // block-uniform

    int srow = lane >> 3;         // 0..7
    int scb  = (lane & 7) ^ srow; // XOR-swizzled global colblk
    const u16* kst = kh + (size_t)(w * 16 + srow) * HD_ + scb * 8;
    const u16* vst = vh + (size_t)(w * 16 + srow) * T_ + scb * 8;
    int swz = (r16 & 7);          // reader-side swizzle

    {
        #pragma unroll
        for (int s2 = 0; s2 < 2; s2++) {
            GLL16(kst + (size_t)(s2 * 8) * HD_, &Kb[0][w * 16 + s2 * 8][0] + lane * 8);
            GLL16(vst + (size_t)(s2 * 8) * T_,  &Vb[0][w * 16 + s2 * 8][0] + lane * 8);
        }
    }
    __syncthreads();

    for (int it = 0; it < n64; ++it) {
        int kv0 = it * 64;
        int buf = it & 1;
        bool lo_on = (it <= ilo_last);
        if (it + 1 < n64) {
            int kvn = kv0 + 64;
            #pragma unroll
            for (int s2 = 0; s2 < 2; s2++) {
                GLL16(kst + (size_t)(kvn + s2 * 8) * HD_, &Kb[buf ^ 1][w * 16 + s2 * 8][0] + lane * 8);
                GLL16(vst + (size_t)(s2 * 8) * T_ + kvn,  &Vb[buf ^ 1][w * 16 + s2 * 8][0] + lane * 8);
            }
        }
        bf16x8 kf[4][2];
        #pragma unroll
        for (int n = 0; n < 4; n++)
            #pragma unroll
            for (int c = 0; c < 2; c++)
                kf[n][c] = *(const bf16x8*)&Kb[buf][n * 16 + r16][((c * 4 + quad) ^ swz) * 8];
        f32x4 sH[4] = {};
        #pragma unroll
        for (int n = 0; n < 4; n++) {
            sH[n] = MFMA(kf[n][0], qh0, sH[n], 0, 0, 0);
            sH[n] = MFMA(kf[n][1], qh1, sH[n], 0, 0, 0);
        }
        if (it == n64 - 1) {
            #pragma unroll
            for (int n = 0; n < 4; n++)
                #pragma unroll
                for (int r = 0; r < 4; r++)
                    if (kv0 + n * 16 + quad * 4 + r > qyH) sH[n][r] = -1e30f;
        }
        #pragma unroll
        for (int n = 0; n < 4; n++) {
            float p0 = __expf(sH[n][0]);
            float p1 = __expf(sH[n][1]);
            float p2 = __expf(sH[n][2]);
            float p3 = __expf(sH[n][3]);
            lH += (p0 + p1) + (p2 + p3);
            uint2 pd; pd.x = pk2bf(p0, p1); pd.y = pk2bf(p2, p3);
            *(uint2*)&P[w][1][r16][n * 16 + quad * 4] = pd;
        }
        if (lo_on) {
            f32x4 sL[4] = {};
            #pragma unroll
            for (int n = 0; n < 4; n++) {
                sL[n] = MFMA(kf[n][0], ql0, sL[n], 0, 0, 0);
                sL[n] = MFMA(kf[n][1], ql1, sL[n], 0, 0, 0);
            }
            if (it == ilo_last) {
                #pragma unroll
                for (int n = 0; n < 4; n++)
                    #pragma unroll
                    for (int r = 0; r < 4; r++)
                        if (kv0 + n * 16 + quad * 4 + r > qyL) sL[n][r] = -1e30f;
            }
            #pragma unroll
            for (int n = 0; n < 4; n++) {
                float p0 = __expf(sL[n][0]);
                float p1 = __expf(sL[n][1]);
                float p2 = __expf(sL[n][2]);
                float p3 = __expf(sL[n][3]);
                lL += (p0 + p1) + (p2 + p3);
                uint2 pd; pd.x = pk2bf(p0, p1); pd.y = pk2bf(p2, p3);
                *(uint2*)&P[w][0][r16][n * 16 + quad * 4] = pd;
            }
        }
        bf16x8 vf[4][2];
        #pragma unroll
        for (int j = 0; j < 4; j++)
            #pragma unroll
            for (int c = 0; c < 2; c++)
                vf[j][c] = *(const bf16x8*)&Vb[buf][j * 16 + r16][((c * 4 + quad) ^ swz) * 8];
        #pragma unroll
        for (int c = 0; c < 2; c++) {
            bf16x8 pfH = *(const bf16x8*)&P[w][1][r16][c * 32 + quad * 8];
            #pragma unroll
            for (int j = 0; j < 4; j++)
                oH[j] = MFMA(vf[j][c], pfH, oH[j], 0, 0, 0);
        }
        if (lo_on) {
            #pragma unroll
            for (int c = 0; c < 2; c++) {
                bf16x8 pfL = *(const bf16x8*)&P[w][0][r16][c * 32 + quad * 8];
                #pragma unroll
                for (int j = 0; j < 4; j++)
                    oL[j] = MFMA(vf[j][c], pfL, oL[j], 0, 0, 0);
            }
        }
        __syncthreads();
    }

    lH += __shfl_xor(lH, 16, 64);
    lH += __shfl_xor(lH, 32, 64);
    lL += __shfl_xor(lL, 16, 64);
    lL += __shfl_xor(lL, 32, 64);
    float invH = 1.f / lH, invL = 1.f / lL;
    int tqH = qb_hi + r16, tqL = qb_lo + r16;
    #pragma unroll
    for (int j = 0; j < 4; j++) {
        ushort4 ovH, ovL;
        ovH.x = f2bf(oH[j][0] * invH); ovH.y = f2bf(oH[j][1] * invH);
        ovH.z = f2bf(oH[j][2] * invH); ovH.w = f2bf(oH[j][3] * invH);
        ovL.x = f2bf(oL[j][0] * invL); ovL.y = f2bf(oL[j][1] * invL);
        ovL.z = f2bf(oL[j][2] * invL); ovL.w = f2bf(oL[j][3] * invL);
        *(ushort4*)(y + ((size_t)b * T_ + tqH) * C_ + h * 64 + j * 16 + quad * 4) = ovH;
        *(ushort4*)(y + ((size_t)b * T_ + tqL) * C_ + h * 64 + j * 16 + quad * 4) = ovL;
    }
}

extern "C" void kernel_launch(void* const* d_in, const int* in_sizes, int n_in,
                              void* d_out, int out_size, void* d_ws, size_t ws_size,
                              hipStream_t stream) {
    const float* x      = (const float*)d_in[0];
    const float* w_attn = (const float*)d_in[1];
    const float* b_attn = (const float*)d_in[2];
    const float* w_proj = (const float*)d_in[3];
    const float* b_proj = (const float*)d_in[4];
    float* out = (float*)d_out;

    char* ws = (char*)d_ws;
    size_t off = 0;
    auto alloc = [&](size_t bytes) {
        void* p = ws + off;
        off += (bytes + 255) & ~(size_t)255;
        return p;
    };
    const size_t M = (size_t)B_ * T_;                    // 8192
    u16* x_bf = (u16*)alloc(M * C_ * 2);                 // [8192][768]
    u16* wat  = (u16*)alloc((size_t)K3_ * C_ * 2);       // [2304][768]
    u16* wpt  = (u16*)alloc((size_t)C_ * C_ * 2);        // [768][768]
    u16* qb   = (u16*)alloc((size_t)B_ * H_ * T_ * HD_ * 2);
    u16* kb   = (u16*)alloc((size_t)B_ * H_ * T_ * HD_ * 2);
    u16* vb   = (u16*)alloc((size_t)B_ * H_ * T_ * HD_ * 2);
    u16* yb   = (u16*)alloc(M * C_ * 2);                 // [8192][768]

    prep<<<6144 + 1728 + 576, 256, 0, stream>>>(x, x_bf, w_attn, wat, w_proj, wpt);
    gemm_qkv<<<768, 512, 0, stream>>>(x_bf, wat, b_attn, qb, kb, vb);
    attn<<<8 * 96, 256, 0, stream>>>(qb, kb, vb, yb);
    gemm_proj<<<256, 512, 0, stream>>>(yb, wpt, b_proj, out);
}